// Round 1
// baseline (1453.429 us; speedup 1.0000x reference)
//
#include <hip/hip_runtime.h>
#include <math.h>

#define Bc 32
#define Lc 512
#define Hc 8
#define Ec 64
#define Sc 512

// One wave per (b,h,l) row of prior. sigma -> Gaussian row, float4 stores.
__global__ __launch_bounds__(256) void prior_kernel(
    const float* __restrict__ sigma, float* __restrict__ prior)
{
    const int wave = threadIdx.x >> 6;
    const int lane = threadIdx.x & 63;
    const int row  = blockIdx.x * 4 + wave;      // (b*H + h)*L + l
    const int l    = row & (Lc - 1);
    const int bh   = row >> 9;                   // b*H + h
    const int b    = bh >> 3;
    const int h    = bh & (Hc - 1);

    float sg = sigma[((size_t)b * Lc + l) * Hc + h];
    sg = 1.0f / (1.0f + __expf(-5.0f * sg)) + 1e-5f;
    sg = expm1f(sg * 1.0986122886681098f);       // 3^sg - 1, no cancellation
    const float inv = 0.3989422804014327f / sg;  // 1/sqrt(2*pi) / sg
    const float c2  = -0.5f / (sg * sg);

    const size_t base = (size_t)row * Sc;
    #pragma unroll
    for (int i = 0; i < 2; ++i) {
        const int s0 = i * 256 + lane * 4;
        const float d0 = (float)(l - (s0 + 0));
        const float d1 = (float)(l - (s0 + 1));
        const float d2 = (float)(l - (s0 + 2));
        const float d3 = (float)(l - (s0 + 3));
        float4 o;
        o.x = inv * __expf(c2 * d0 * d0);
        o.y = inv * __expf(c2 * d1 * d1);
        o.z = inv * __expf(c2 * d2 * d2);
        o.w = inv * __expf(c2 * d3 * d3);
        *(float4*)&prior[base + s0] = o;
    }
}

// Block = (b, h, 16-row l-tile). Scores -> softmax -> series write -> P@V.
__global__ __launch_bounds__(256) void attn_kernel(
    const float* __restrict__ Q, const float* __restrict__ K,
    const float* __restrict__ V, float* __restrict__ outV,
    float* __restrict__ series)
{
    __shared__ float Qs[16 * 64];    //  4 KB, Q tile row-major
    __shared__ float KT[64 * 128];   // 32 KB: scores phase KT[e][c]; V phase VT[c][e]
    __shared__ float Pb[16 * 512];   // 32 KB: full score/prob rows for this tile

    const int t    = threadIdx.x;
    const int wave = t >> 6;
    const int lane = t & 63;
    const int h    = blockIdx.y;
    const int b    = blockIdx.z;
    const int l0   = blockIdx.x * 16;

    const size_t qbase = (((size_t)b * Lc + l0) * Hc + h) * Ec;
    const size_t kbase = (((size_t)b * Lc) * Hc + h) * Ec;   // + s*(H*E)

    // ---- load Q tile (16x64) ----
    {
        const int r  = t >> 4;
        const int e4 = (t & 15) * 4;
        const float4 v = *(const float4*)&Q[qbase + (size_t)r * (Hc * Ec) + e4];
        *(float4*)&Qs[r * 64 + e4] = v;
    }

    const int r0 = wave * 4;       // this wave's 4 rows
    const int cl = lane * 2;       // this lane's 2 cols within a 128-col K tile

    // ---- scores: S = scale * Q K^T, tiled 128 cols at a time ----
    for (int kt = 0; kt < 4; ++kt) {
        const int cb = kt * 128;
        __syncthreads();           // previous tile's readers done (also covers Qs)
        {   // stage K tile transposed: KT[e][c]; conflict-free LDS writes
            const int c  = t & 127;
            const int eb = (t >> 7) * 4;
            const float* kp = &K[kbase + (size_t)(cb + c) * (Hc * Ec)];
            #pragma unroll
            for (int i = 0; i < 8; ++i) {
                const int e4 = eb + 8 * i;
                const float4 v = *(const float4*)&kp[e4];
                KT[(e4 + 0) * 128 + c] = v.x;
                KT[(e4 + 1) * 128 + c] = v.y;
                KT[(e4 + 2) * 128 + c] = v.z;
                KT[(e4 + 3) * 128 + c] = v.w;
            }
        }
        __syncthreads();
        float s00=0,s01=0,s10=0,s11=0,s20=0,s21=0,s30=0,s31=0;
        #pragma unroll
        for (int e4 = 0; e4 < 64; e4 += 4) {
            const float4 q0 = *(const float4*)&Qs[(r0+0)*64 + e4];  // broadcast reads
            const float4 q1 = *(const float4*)&Qs[(r0+1)*64 + e4];
            const float4 q2 = *(const float4*)&Qs[(r0+2)*64 + e4];
            const float4 q3 = *(const float4*)&Qs[(r0+3)*64 + e4];
            const float2 k0 = *(const float2*)&KT[(e4+0)*128 + cl]; // conflict-free
            const float2 k1 = *(const float2*)&KT[(e4+1)*128 + cl];
            const float2 k2 = *(const float2*)&KT[(e4+2)*128 + cl];
            const float2 k3 = *(const float2*)&KT[(e4+3)*128 + cl];
            s00 += q0.x*k0.x + q0.y*k1.x + q0.z*k2.x + q0.w*k3.x;
            s01 += q0.x*k0.y + q0.y*k1.y + q0.z*k2.y + q0.w*k3.y;
            s10 += q1.x*k0.x + q1.y*k1.x + q1.z*k2.x + q1.w*k3.x;
            s11 += q1.x*k0.y + q1.y*k1.y + q1.z*k2.y + q1.w*k3.y;
            s20 += q2.x*k0.x + q2.y*k1.x + q2.z*k2.x + q2.w*k3.x;
            s21 += q2.x*k0.y + q2.y*k1.y + q2.z*k2.y + q2.w*k3.y;
            s30 += q3.x*k0.x + q3.y*k1.x + q3.z*k2.x + q3.w*k3.x;
            s31 += q3.x*k0.y + q3.y*k1.y + q3.z*k2.y + q3.w*k3.y;
        }
        const float sc = 0.125f;   // 1/sqrt(64)
        *(float2*)&Pb[(r0+0)*512 + cb + cl] = make_float2(s00*sc, s01*sc);
        *(float2*)&Pb[(r0+1)*512 + cb + cl] = make_float2(s10*sc, s11*sc);
        *(float2*)&Pb[(r0+2)*512 + cb + cl] = make_float2(s20*sc, s21*sc);
        *(float2*)&Pb[(r0+3)*512 + cb + cl] = make_float2(s30*sc, s31*sc);
    }

    // ---- softmax per row (wave owns its 4 rows; same-wave LDS, no barrier needed) ----
    #pragma unroll
    for (int r = 0; r < 4; ++r) {
        const int row = r0 + r;
        float v[8];
        float m = -3.0e38f;
        #pragma unroll
        for (int k = 0; k < 8; ++k) {
            v[k] = Pb[row*512 + lane + 64*k];
            m = fmaxf(m, v[k]);
        }
        #pragma unroll
        for (int off = 32; off > 0; off >>= 1) m = fmaxf(m, __shfl_xor(m, off));
        float ssum = 0.0f;
        #pragma unroll
        for (int k = 0; k < 8; ++k) { v[k] = __expf(v[k] - m); ssum += v[k]; }
        #pragma unroll
        for (int off = 32; off > 0; off >>= 1) ssum += __shfl_xor(ssum, off);
        const float is = 1.0f / ssum;
        const size_t srow = ((size_t)(b * Hc + h) * Lc + (l0 + row)) * Sc;
        #pragma unroll
        for (int k = 0; k < 8; ++k) {
            const float p = v[k] * is;
            Pb[row*512 + lane + 64*k] = p;     // keep normalized probs for P@V
            series[srow + lane + 64*k] = p;    // coalesced b32 stores
        }
    }

    // ---- V = P @ values: thread owns (row, 4 e's) ----
    const int vr = t >> 4;          // row 0..15 (within this wave's rows)
    const int e4 = (t & 15) * 4;
    float4 acc = make_float4(0.f, 0.f, 0.f, 0.f);
    for (int ct = 0; ct < 4; ++ct) {
        const int cb = ct * 128;
        __syncthreads();            // everyone past scores/softmax; KT free to reuse
        {   // stage V tile: VT[c][e], coalesced global + conflict-free LDS
            #pragma unroll
            for (int i = 0; i < 8; ++i) {
                const int q  = t + 256 * i;
                const int c  = q >> 4;
                const int ee = (q & 15) * 4;
                const float4 vv = *(const float4*)&V[kbase + (size_t)(cb + c) * (Hc * Ec) + ee];
                *(float4*)&KT[c * 64 + ee] = vv;
            }
        }
        __syncthreads();
        #pragma unroll
        for (int c = 0; c < 128; c += 4) {
            const float4 p  = *(const float4*)&Pb[vr * 512 + cb + c];  // 4-addr broadcast
            const float4 v0 = *(const float4*)&KT[(c+0)*64 + e4];
            const float4 v1 = *(const float4*)&KT[(c+1)*64 + e4];
            const float4 v2 = *(const float4*)&KT[(c+2)*64 + e4];
            const float4 v3 = *(const float4*)&KT[(c+3)*64 + e4];
            acc.x += p.x*v0.x + p.y*v1.x + p.z*v2.x + p.w*v3.x;
            acc.y += p.x*v0.y + p.y*v1.y + p.z*v2.y + p.w*v3.y;
            acc.z += p.x*v0.z + p.y*v1.z + p.z*v2.z + p.w*v3.z;
            acc.w += p.x*v0.w + p.y*v1.w + p.z*v2.w + p.w*v3.w;
        }
    }
    *(float4*)&outV[qbase + (size_t)vr * (Hc * Ec) + e4] = acc;
}

extern "C" void kernel_launch(void* const* d_in, const int* in_sizes, int n_in,
                              void* d_out, int out_size, void* d_ws, size_t ws_size,
                              hipStream_t stream) {
    const float* Q  = (const float*)d_in[0];
    const float* K  = (const float*)d_in[1];
    const float* Vv = (const float*)d_in[2];
    const float* sg = (const float*)d_in[3];

    float* outV   = (float*)d_out;                                   // [B,L,H,E]
    float* series = outV + (size_t)Bc * Lc * Hc * Ec;                // [B,H,L,S]
    float* prior  = series + (size_t)Bc * Hc * Lc * Sc;              // [B,H,L,S]

    prior_kernel<<<(Bc * Hc * Lc) / 4, 256, 0, stream>>>(sg, prior);
    attn_kernel<<<dim3(Lc / 16, Hc, Bc), 256, 0, stream>>>(Q, K, Vv, outV, series);
}

// Round 2
// 853.598 us; speedup vs baseline: 1.7027x; 1.7027x over previous
//
#include <hip/hip_runtime.h>
#include <hip/hip_bf16.h>
#include <math.h>

#define Bc 32
#define Lc 512
#define Hc 8
#define Ec 64
#define Sc 512

typedef __attribute__((ext_vector_type(8))) short short8;
typedef __attribute__((ext_vector_type(4))) float f32x4;

// ---------- helpers ----------
__device__ inline unsigned short f2bf(float x) {           // fp32 -> bf16 RNE
    unsigned u = __float_as_uint(x);
    return (unsigned short)((u + 0x7fffu + ((u >> 16) & 1u)) >> 16);
}
__device__ inline float bf2f(unsigned short s) {
    return __uint_as_float(((unsigned)s) << 16);
}
__device__ inline unsigned packql(float x) {               // (hi16<<16)|lo16 split
    unsigned short hi = f2bf(x);
    float lo = x - bf2f(hi);
    return (((unsigned)hi) << 16) | (unsigned)f2bf(lo);
}
__device__ inline void unpack_frags(uint4 a, uint4 b, short8& h, short8& l) {
    h[0]=(short)(a.x>>16); h[1]=(short)(a.y>>16); h[2]=(short)(a.z>>16); h[3]=(short)(a.w>>16);
    h[4]=(short)(b.x>>16); h[5]=(short)(b.y>>16); h[6]=(short)(b.z>>16); h[7]=(short)(b.w>>16);
    l[0]=(short)(a.x&0xffff); l[1]=(short)(a.y&0xffff); l[2]=(short)(a.z&0xffff); l[3]=(short)(a.w&0xffff);
    l[4]=(short)(b.x&0xffff); l[5]=(short)(b.y&0xffff); l[6]=(short)(b.z&0xffff); l[7]=(short)(b.w&0xffff);
}

// ---------- pack kernels ----------
// Q/K fp32 [b][s][h][e] -> uint32 (bf16hi|bf16lo) [b][h][s][e]
__global__ __launch_bounds__(256) void pack_qk(const float* __restrict__ src,
                                               unsigned* __restrict__ dst) {
    const int t = threadIdx.x;
    const int b = blockIdx.z, h = blockIdx.y, s0 = blockIdx.x * 32;
    const int e4 = (t & 15) * 4;
    const int sr = t >> 4;                       // 0..15
    #pragma unroll
    for (int i = 0; i < 2; ++i) {
        const int s = s0 + sr + 16 * i;
        const float4 v = *(const float4*)&src[(((size_t)b * Lc + s) * Hc + h) * Ec + e4];
        uint4 o;
        o.x = packql(v.x); o.y = packql(v.y); o.z = packql(v.z); o.w = packql(v.w);
        *(uint4*)&dst[(((size_t)b * Hc + h) * Lc + s) * Ec + e4] = o;
    }
}

// V fp32 [b][s][h][e] -> bf16 V^T [b][h][e][s]
__global__ __launch_bounds__(256) void pack_vt(const float* __restrict__ V,
                                               unsigned short* __restrict__ Vt) {
    __shared__ float LT[64 * 68];
    const int t = threadIdx.x;
    const int b = blockIdx.z, h = blockIdx.y, s0 = blockIdx.x * 64;
    #pragma unroll
    for (int i = 0; i < 16; ++i) {
        const int idx = t + 256 * i;
        const int e = idx & 63, s = idx >> 6;
        LT[e * 68 + s] = V[(((size_t)b * Lc + s0 + s) * Hc + h) * Ec + e];
    }
    __syncthreads();
    #pragma unroll
    for (int i = 0; i < 16; ++i) {
        const int idx = t + 256 * i;
        const int s = idx & 63, e = idx >> 6;
        Vt[((size_t)(b * Hc + h) * Ec + e) * Sc + s0 + s] = f2bf(LT[e * 68 + s]);
    }
}

// ---------- prior ----------
__global__ __launch_bounds__(256) void prior_kernel(
    const float* __restrict__ sigma, float* __restrict__ prior)
{
    const int wave = threadIdx.x >> 6;
    const int lane = threadIdx.x & 63;
    const int row  = blockIdx.x * 4 + wave;      // (b*H+h)*L + l
    const int l    = row & (Lc - 1);
    const int bh   = row >> 9;
    const int b    = bh >> 3;
    const int h    = bh & (Hc - 1);

    float sg = sigma[((size_t)b * Lc + l) * Hc + h];
    sg = 1.0f / (1.0f + __expf(-5.0f * sg)) + 1e-5f;
    sg = expm1f(sg * 1.0986122886681098f);
    const float inv = 0.3989422804014327f / sg;
    const float c2  = -0.5f / (sg * sg);

    const size_t base = (size_t)row * Sc;
    #pragma unroll
    for (int i = 0; i < 2; ++i) {
        const int s0 = i * 256 + lane * 4;
        const float d0 = (float)(l - (s0 + 0));
        const float d1 = (float)(l - (s0 + 1));
        const float d2 = (float)(l - (s0 + 2));
        const float d3 = (float)(l - (s0 + 3));
        float4 o;
        o.x = inv * __expf(c2 * d0 * d0);
        o.y = inv * __expf(c2 * d1 * d1);
        o.z = inv * __expf(c2 * d2 * d2);
        o.w = inv * __expf(c2 * d3 * d3);
        *(float4*)&prior[base + s0] = o;
    }
}

// ---------- fused attention (MFMA) ----------
// 128 thr = 2 waves; block tile = 32 rows x 512 cols; wave = 16 rows.
__global__ __launch_bounds__(128, 2) void attn_mfma(
    const unsigned* __restrict__ Qpk, const unsigned* __restrict__ Kpk,
    const unsigned short* __restrict__ Vt, float* __restrict__ outV,
    float* __restrict__ series)
{
    __shared__ short Pb[32 * 520];   // probs, bf16, pitch 520 (b128-aligned, ~2-way banks)
    __shared__ short VT[64 * 72];    // V^T s-tile, pitch 72 (16B-aligned, 2-way banks)

    const int t    = threadIdx.x;
    const int lane = t & 63, wave = t >> 6;
    const int quad = lane >> 4, l16 = lane & 15;
    const int b = blockIdx.z, h = blockIdx.y, l0 = blockIdx.x * 32;
    const int bh = b * Hc + h;
    const size_t kb = (size_t)bh * Lc * Ec;

    // ---- A fragments: Q rows (hi/lo split), layout A[m=lane&15][k=quad*8+j] ----
    short8 qh[2], ql[2];
    {
        const int qrow = l0 + wave * 16 + l16;
        #pragma unroll
        for (int kt = 0; kt < 2; ++kt) {
            const uint4* qp = (const uint4*)&Qpk[kb + (size_t)qrow * Ec + kt * 32 + quad * 8];
            unpack_frags(qp[0], qp[1], qh[kt], ql[kt]);
        }
    }

    // ---- QK^T: 32 n-tiles of 16 cols, split-bf16 (3 MFMAs per k-tile) ----
    f32x4 acc[32];
    #pragma unroll
    for (int nt = 0; nt < 32; ++nt) { acc[nt][0]=0.f; acc[nt][1]=0.f; acc[nt][2]=0.f; acc[nt][3]=0.f; }

    #pragma unroll
    for (int nt = 0; nt < 32; ++nt) {
        const int s = nt * 16 + l16;             // B frag: n = lane&15 (key index)
        #pragma unroll
        for (int kt = 0; kt < 2; ++kt) {
            const uint4* kp = (const uint4*)&Kpk[kb + (size_t)s * Ec + kt * 32 + quad * 8];
            short8 kh, kl;
            unpack_frags(kp[0], kp[1], kh, kl);
            acc[nt] = __builtin_amdgcn_mfma_f32_16x16x32_bf16(qh[kt], kh, acc[nt], 0, 0, 0);
            acc[nt] = __builtin_amdgcn_mfma_f32_16x16x32_bf16(qh[kt], kl, acc[nt], 0, 0, 0);
            acc[nt] = __builtin_amdgcn_mfma_f32_16x16x32_bf16(ql[kt], kh, acc[nt], 0, 0, 0);
        }
    }

    // ---- softmax: rows fully in-wave (row = quad*4+reg, cols = nt*16+lane&15) ----
    #pragma unroll
    for (int r = 0; r < 4; ++r) {
        float m = acc[0][r];
        #pragma unroll
        for (int nt = 1; nt < 32; ++nt) m = fmaxf(m, acc[nt][r]);
        m = fmaxf(m, __shfl_xor(m, 1)); m = fmaxf(m, __shfl_xor(m, 2));
        m = fmaxf(m, __shfl_xor(m, 4)); m = fmaxf(m, __shfl_xor(m, 8));
        float ssum = 0.f;
        #pragma unroll
        for (int nt = 0; nt < 32; ++nt) {
            const float e = __expf((acc[nt][r] - m) * 0.125f);   // scale = 1/sqrt(64)
            acc[nt][r] = e; ssum += e;
        }
        ssum += __shfl_xor(ssum, 1); ssum += __shfl_xor(ssum, 2);
        ssum += __shfl_xor(ssum, 4); ssum += __shfl_xor(ssum, 8);
        const float is = 1.f / ssum;
        #pragma unroll
        for (int nt = 0; nt < 32; ++nt) acc[nt][r] *= is;
    }

    // ---- stash normalized probs to LDS as bf16 (A-frag friendly layout) ----
    #pragma unroll
    for (int nt = 0; nt < 32; ++nt) {
        #pragma unroll
        for (int r = 0; r < 4; ++r) {
            const int row = wave * 16 + quad * 4 + r;
            Pb[row * 520 + nt * 16 + l16] = (short)f2bf(acc[nt][r]);
        }
    }
    __syncthreads();

    // ---- coalesced series write (bf16-rounded, same values PV uses) ----
    {
        const int col8 = (t & 63) * 8;
        #pragma unroll
        for (int k = 0; k < 16; ++k) {
            const int row = (t >> 6) + 2 * k;    // 0..31
            const short8 v = *(const short8*)&Pb[row * 520 + col8];
            float4 f0, f1;
            f0.x = bf2f((unsigned short)v[0]); f0.y = bf2f((unsigned short)v[1]);
            f0.z = bf2f((unsigned short)v[2]); f0.w = bf2f((unsigned short)v[3]);
            f1.x = bf2f((unsigned short)v[4]); f1.y = bf2f((unsigned short)v[5]);
            f1.z = bf2f((unsigned short)v[6]); f1.w = bf2f((unsigned short)v[7]);
            float* sp = &series[((size_t)bh * Lc + l0 + row) * Sc + col8];
            *(float4*)sp = f0;
            *(float4*)(sp + 4) = f1;
        }
    }

    // ---- P @ V: wave = 16 rows x 64 e; V^T staged per 64-s tile ----
    f32x4 oacc[4];
    #pragma unroll
    for (int et = 0; et < 4; ++et) { oacc[et][0]=0.f; oacc[et][1]=0.f; oacc[et][2]=0.f; oacc[et][3]=0.f; }

    for (int st = 0; st < 8; ++st) {
        __syncthreads();
        {   // stage VT[e][0..63] from global V^T (pure b128 copies)
            const int e = t & 63, sb = t >> 6;   // sb in {0,1}: 32 s each
            const short8* src = (const short8*)&Vt[((size_t)bh * Ec + e) * Sc + st * 64 + sb * 32];
            short8* dst = (short8*)&VT[e * 72 + sb * 32];
            dst[0] = src[0]; dst[1] = src[1]; dst[2] = src[2]; dst[3] = src[3];
        }
        __syncthreads();
        #pragma unroll
        for (int kt2 = 0; kt2 < 2; ++kt2) {
            const short8 af = *(const short8*)&Pb[(wave * 16 + l16) * 520 + st * 64 + kt2 * 32 + quad * 8];
            #pragma unroll
            for (int et = 0; et < 4; ++et) {
                const short8 bf = *(const short8*)&VT[(et * 16 + l16) * 72 + kt2 * 32 + quad * 8];
                oacc[et] = __builtin_amdgcn_mfma_f32_16x16x32_bf16(af, bf, oacc[et], 0, 0, 0);
            }
        }
    }

    // ---- epilogue: outV [B][L][H][E] ----
    #pragma unroll
    for (int et = 0; et < 4; ++et) {
        #pragma unroll
        for (int r = 0; r < 4; ++r) {
            const int l = l0 + wave * 16 + quad * 4 + r;
            outV[(((size_t)b * Lc + l) * Hc + h) * Ec + et * 16 + l16] = oacc[et][r];
        }
    }
}

extern "C" void kernel_launch(void* const* d_in, const int* in_sizes, int n_in,
                              void* d_out, int out_size, void* d_ws, size_t ws_size,
                              hipStream_t stream) {
    (void)d_ws; (void)ws_size; (void)n_in; (void)in_sizes;
    const float* Q  = (const float*)d_in[0];
    const float* K  = (const float*)d_in[1];
    const float* Vv = (const float*)d_in[2];
    const float* sg = (const float*)d_in[3];

    float* outV   = (float*)d_out;                               // [B,L,H,E]
    float* series = outV + (size_t)Bc * Lc * Hc * Ec;            // [B,H,L,S]
    float* prior  = series + (size_t)Bc * Hc * Lc * Sc;          // [B,H,L,S]

    // Scratch for packed operands lives inside the prior region (84MB < 268MB);
    // prior_kernel runs last and overwrites it.
    unsigned*       Qpk = (unsigned*)prior;
    unsigned*       Kpk = Qpk + (size_t)Bc * Lc * Hc * Ec;
    unsigned short* Vt  = (unsigned short*)(Kpk + (size_t)Bc * Lc * Hc * Ec);

    pack_qk<<<dim3(Lc / 32, Hc, Bc), 256, 0, stream>>>(Q, Qpk);
    pack_qk<<<dim3(Lc / 32, Hc, Bc), 256, 0, stream>>>(K, Kpk);
    pack_vt<<<dim3(Lc / 64, Hc, Bc), 256, 0, stream>>>(Vv, Vt);
    attn_mfma<<<dim3(Lc / 32, Hc, Bc), 128, 0, stream>>>(Qpk, Kpk, Vt, outV, series);
    prior_kernel<<<(Bc * Hc * Lc) / 4, 256, 0, stream>>>(sg, prior);
}